// Round 10
// baseline (163.889 us; speedup 1.0000x reference)
//
#include <hip/hip_runtime.h>
#include <hip/hip_bf16.h>

typedef __attribute__((ext_vector_type(4))) float f32x4;
typedef __attribute__((ext_vector_type(16))) float f32x16;
typedef __attribute__((ext_vector_type(8))) short short8;

#define LOG2E 1.4426950408889634f

__device__ __forceinline__ unsigned short f2bf(float f) {
  union { float f; unsigned u; } v; v.f = f;
  unsigned r = v.u + 0x7FFFu + ((v.u >> 16) & 1u);
  return (unsigned short)(r >> 16);
}

__device__ __forceinline__ float bf2f(unsigned short u) {
  union { unsigned u; float f; } v; v.u = ((unsigned)u) << 16;
  return v.f;
}

__device__ __forceinline__ void gload_lds16(const unsigned short* g, unsigned short* l) {
  __builtin_amdgcn_global_load_lds((const __attribute__((address_space(1))) void*)g,
                                   (__attribute__((address_space(3))) void*)l, 16, 0, 0);
}

// ---------------- f32 -> bf16 conversion + mask nonzero flag ----------------
__global__ void cvt_kernel(const float* __restrict__ qin, const float* __restrict__ kin,
                           const float* __restrict__ vin,
                           const float* __restrict__ wq, const float* __restrict__ wk,
                           const float* __restrict__ wv, const float* __restrict__ wo,
                           const float* __restrict__ mask,
                           unsigned short* __restrict__ xq, unsigned short* __restrict__ xk,
                           unsigned short* __restrict__ xv,
                           unsigned short* __restrict__ wqb, unsigned short* __restrict__ wkb,
                           unsigned short* __restrict__ wvb, unsigned short* __restrict__ wob,
                           int* __restrict__ flag) {
  const size_t M1 = 1048576;
  size_t u = (size_t)blockIdx.x * 256 + threadIdx.x;
  const float* src; unsigned short* dst; size_t loc;
  if (u < M1)                 { src = qin; dst = xq;  loc = u; }
  else if (u < 2*M1)          { src = kin; dst = xk;  loc = u - M1; }
  else if (u < 3*M1)          { src = vin; dst = xv;  loc = u - 2*M1; }
  else if (u < 3*M1 + 262144) { src = wq;  dst = wqb; loc = u - 3*M1; }
  else if (u < 3*M1 + 524288) { src = wk;  dst = wkb; loc = u - (3*M1 + 262144); }
  else if (u < 3*M1 + 786432) { src = wv;  dst = wvb; loc = u - (3*M1 + 524288); }
  else if (u < 4*M1)          { src = wo;  dst = wob; loc = u - (3*M1 + 786432); }
  else {
    loc = u - 4*M1;
    float4 f = ((const float4*)mask)[loc];
    if (f.x != 0.f || f.y != 0.f || f.z != 0.f || f.w != 0.f) atomicOr(flag, 1);
    return;
  }
  float4 f = ((const float4*)src)[loc];
  ushort4 o;
  o.x = f2bf(f.x); o.y = f2bf(f.y); o.z = f2bf(f.z); o.w = f2bf(f.w);
  ((ushort4*)dst)[loc] = o;
}

// ---------------- GEMM core: C[M,N] = A[M,K] * B[N,K]^T, bf16 in, f32 acc ----
// BM=BN=128, BK=32, 512 threads (8 waves, 4m x 2n; per-wave 32x64 output).
// Double-buffered LDS (1 barrier per K-step). XOR-swizzled tiles: LDS dest
// linear for global_load_lds, SOURCE column-group pre-swizzled with
// g ^= (row>>1)&3, reader applies the same involution -> conflict-free.
__device__ __forceinline__ void gemm_bt_core(const unsigned short* __restrict__ A,
                                             const unsigned short* __restrict__ B,
                                             unsigned short* As, unsigned short* Bs,
                                             int m0, int n0, f32x4 acc[2][4]) {
  const int t = threadIdx.x, lane = t & 63, w = t >> 6;
  const int wr = (w >> 1) << 5;  // wave m-base: 0..96
  const int wc = (w & 1) << 6;   // wave n-base: 0,64
  const int lo = lane & 15, hi = lane >> 4;
  const int swz = (hi ^ ((lo >> 1) & 3)) * 8;  // reader's column-group XOR
#pragma unroll
  for (int i = 0; i < 2; ++i)
#pragma unroll
    for (int j = 0; j < 4; ++j) acc[i][j] = f32x4{0.f, 0.f, 0.f, 0.f};

  const int c0 = t, row0 = c0 >> 2;
  const int gsw0 = ((c0 & 3) ^ ((row0 >> 1) & 3)) << 3;
  const unsigned short* Ar0 = A + (size_t)(m0 + row0) * 1024 + gsw0;
  const unsigned short* Br0 = B + (size_t)(n0 + row0) * 1024 + gsw0;

  auto stage = [&](int kt, int buf) {
    gload_lds16(Ar0 + kt, &As[buf * 4096 + c0 * 8]);
    gload_lds16(Br0 + kt, &Bs[buf * 4096 + c0 * 8]);
  };

  stage(0, 0);
  for (int it = 0; it < 32; ++it) {
    __syncthreads();  // drains vmcnt(0): buf it&1 ready; buf (it+1)&1 free
    if (it + 1 < 32) stage((it + 1) * 32, (it + 1) & 1);
    const unsigned short* Ac = &As[(it & 1) * 4096];
    const unsigned short* Bc = &Bs[(it & 1) * 4096];
    short8 af[2], bfr[4];
#pragma unroll
    for (int i = 0; i < 2; ++i) af[i]  = *(const short8*)&Ac[(wr + i*16 + lo) * 32 + swz];
#pragma unroll
    for (int j = 0; j < 4; ++j) bfr[j] = *(const short8*)&Bc[(wc + j*16 + lo) * 32 + swz];
#pragma unroll
    for (int i = 0; i < 2; ++i)
#pragma unroll
      for (int j = 0; j < 4; ++j)
        acc[i][j] = __builtin_amdgcn_mfma_f32_16x16x32_bf16(af[i], bfr[j], acc[i][j], 0, 0, 0);
  }
}

// ---------------- QKV projections ----------------
__global__ __launch_bounds__(512)
void gemm_qkv_kernel(const unsigned short* __restrict__ xq, const unsigned short* __restrict__ xk,
                     const unsigned short* __restrict__ xv,
                     const unsigned short* __restrict__ wq, const unsigned short* __restrict__ wk,
                     const unsigned short* __restrict__ wv,
                     unsigned short* __restrict__ Qbf, unsigned short* __restrict__ Kbf,
                     unsigned short* __restrict__ Vt,
                     float* __restrict__ kcache, float* __restrict__ vcache) {
  __shared__ __align__(16) unsigned short As[2 * 4096];
  __shared__ __align__(16) unsigned short Bs[2 * 4096];
  const int z = blockIdx.z;
  const unsigned short* A = (z == 0) ? xq : (z == 1) ? xk : xv;
  const unsigned short* B = (z == 0) ? wq : (z == 1) ? wk : wv;
  const int m0 = blockIdx.x * 128, n0 = blockIdx.y * 128;
  f32x4 acc[2][4];
  gemm_bt_core(A, B, As, Bs, m0, n0, acc);
  const int t = threadIdx.x, lane = t & 63, w = t >> 6;
  const int wr = (w >> 1) << 5, wc = (w & 1) << 6;
  const int lo = lane & 15, hi = lane >> 4;
#pragma unroll
  for (int i = 0; i < 2; ++i)
#pragma unroll
    for (int j = 0; j < 4; ++j) {
      int n = n0 + wc + j * 16 + lo;
      int head = n >> 6, dk = n & 63;
      int mbase = m0 + wr + i * 16 + hi * 4;
      int b = mbase >> 11, sbase = mbase & 2047;
      size_t bh = (size_t)b * 16 + head;
      if (z == 0) {
#pragma unroll
        for (int r = 0; r < 4; ++r)
          Qbf[(bh * 2048 + sbase + r) * 64 + dk] = f2bf(acc[i][j][r] * LOG2E);
      } else if (z == 1) {
#pragma unroll
        for (int r = 0; r < 4; ++r)
          Kbf[(bh * 2048 + sbase + r) * 64 + dk] = f2bf(acc[i][j][r]);
        float4 kv4;
        kv4.x = acc[i][j][0]; kv4.y = acc[i][j][1];
        kv4.z = acc[i][j][2]; kv4.w = acc[i][j][3];
        *(float4*)&kcache[(bh * 64 + dk) * 2048 + sbase] = kv4;
      } else {
#pragma unroll
        for (int r = 0; r < 4; ++r)
          vcache[(bh * 2048 + sbase + r) * 64 + dk] = acc[i][j][r];
        ushort4 vt4;
        vt4.x = f2bf(acc[i][j][0]); vt4.y = f2bf(acc[i][j][1]);
        vt4.z = f2bf(acc[i][j][2]); vt4.w = f2bf(acc[i][j][3]);
        *(ushort4*)&Vt[(bh * 64 + dk) * 2048 + sbase] = vt4;
      }
    }
}

// ---------------- output projection ----------------
__global__ __launch_bounds__(512)
void gemm_o_kernel(const unsigned short* __restrict__ A, const unsigned short* __restrict__ B,
                   float* __restrict__ C) {
  __shared__ __align__(16) unsigned short As[2 * 4096];
  __shared__ __align__(16) unsigned short Bs[2 * 4096];
  const int m0 = blockIdx.x * 128, n0 = blockIdx.y * 128;
  f32x4 acc[2][4];
  gemm_bt_core(A, B, As, Bs, m0, n0, acc);
  const int t = threadIdx.x, lane = t & 63, w = t >> 6;
  const int wr = (w >> 1) << 5, wc = (w & 1) << 6;
  const int lo = lane & 15, hi = lane >> 4;
#pragma unroll
  for (int i = 0; i < 2; ++i)
#pragma unroll
    for (int j = 0; j < 4; ++j)
#pragma unroll
      for (int r = 0; r < 4; ++r)
        C[(size_t)(m0 + wr + i * 16 + hi * 4 + r) * 1024 + n0 + wc + j * 16 + lo] = acc[i][j][r];
}

// ---------------- flash attention, swapped-operand 32x32 MFMA ----------------
// KV-split x2 on the round-8 window structure: 512-thread blocks (8 waves x
// 32 q-rows), grid (8,32,2) = 512 blocks -> 2 blocks/CU x 8 waves = 16
// waves/CU = 4 waves/SIMD (2x round 8). 4 KV buffer pairs (64KB LDS), ONE
// barrier per TWO tiles, compute order QK(A) -> QK(B) -> exp(A) -> PV(A) ->
// exp(B) -> PV(B). Each block accumulates the UNNORMALIZED O-partial +
// l-partial over its 16-tile KV half (scale-invariant softmax: partials sum
// exactly). Scale-invariant softmax in log2 domain (Q pre-scaled by log2e).
__global__ __launch_bounds__(512, 4)
void attn_kernel(const unsigned short* __restrict__ Qbf,
                 const unsigned short* __restrict__ Kbf,
                 const unsigned short* __restrict__ Vtb,
                 const float* __restrict__ mask, const int* __restrict__ flag,
                 unsigned short* __restrict__ Op0, unsigned short* __restrict__ Op1,
                 float* __restrict__ lpart) {
  __shared__ __align__(16) unsigned short Ks[4 * 4096];  // [buf][d8][slot64][8]
  __shared__ __align__(16) unsigned short Vs[4 * 4096];  // [buf][s8][dk64][8]
  const int t = threadIdx.x, lane = t & 63, w = t >> 6;
  const int q31 = lane & 31, hh = lane >> 5;

  // XCD-aware swizzle: 512 blocks, 8 XCDs -> 64 logical-contiguous per XCD
  // (4 bh each, 16 blocks per bh: 8 qtiles x 2 KV-halves).
  int orig = blockIdx.x + 8 * blockIdx.y + 256 * blockIdx.z;
  int logical = (orig & 7) * 64 + (orig >> 3);
  const int bh = logical >> 4;
  const int rem = logical & 15;
  const int qtile = rem >> 1, half = rem & 1;
  const int b = bh >> 4, head = bh & 15;
  const int q = qtile * 256 + w * 32 + q31;
  const int mf = *flag;

  short8 qf[4];
  const unsigned short* Qrow = Qbf + ((size_t)bh * 2048 + q) * 64 + hh * 8;
#pragma unroll
  for (int kk = 0; kk < 4; ++kk) qf[kk] = *(const short8*)(Qrow + kk * 16);

  f32x16 o[2], zero16;
#pragma unroll
  for (int d = 0; d < 2; ++d)
#pragma unroll
    for (int r = 0; r < 16; ++r) o[d][r] = 0.f;
#pragma unroll
  for (int r = 0; r < 16; ++r) zero16[r] = 0.f;
  float rs4[4] = {0.f, 0.f, 0.f, 0.f};

  const unsigned short* Kbase = Kbf + (size_t)bh * 2048 * 64;
  const unsigned short* Vbase = Vtb + (size_t)bh * 64 * 2048;

  auto stage = [&](int st, int buf) {
    int c = t;  // 512 threads cover one 8KB buffer per tensor
    int hi6 = c >> 6, lo6 = c & 63;
    int pr = (lo6 & ~12) | ((lo6 & 4) << 1) | ((lo6 >> 1) & 4);  // bit2<->bit3
    gload_lds16(Kbase + (size_t)(st * 64 + pr) * 64 + hi6 * 8, &Ks[buf * 4096 + c * 8]);
    gload_lds16(Vbase + (size_t)lo6 * 2048 + st * 64 + hi6 * 8, &Vs[buf * 4096 + c * 8]);
  };

  auto qk_tile = [&](const unsigned short* Kc, f32x16 (&sf)[2]) {
#pragma unroll
    for (int kk = 0; kk < 4; ++kk)
#pragma unroll
      for (int i = 0; i < 2; ++i) {
        short8 kf = *(const short8*)&Kc[((kk * 2 + hh) * 64 + i * 32 + q31) * 8];
        sf[i] = __builtin_amdgcn_mfma_f32_32x32x16_bf16(kf, qf[kk],
                                                        kk == 0 ? zero16 : sf[i], 0, 0, 0);
      }
  };

  auto softmax_tile = [&](f32x16 (&sf)[2], int st, unsigned (&pw)[2][8]) {
    if (mf) {
      const float* mrow = mask + (size_t)q * 2048 + st * 64;
#pragma unroll
      for (int i = 0; i < 2; ++i)
#pragma unroll
        for (int r = 0; r < 16; ++r)
          sf[i][r] += mrow[32 * i + (r & 7) + 16 * ((r >> 3) & 1) + 8 * hh] * LOG2E;
    }
#pragma unroll
    for (int i = 0; i < 2; ++i)
#pragma unroll
      for (int v = 0; v < 8; ++v) {
        float p0 = __builtin_amdgcn_exp2f(sf[i][2 * v]);
        float p1 = __builtin_amdgcn_exp2f(sf[i][2 * v + 1]);
        rs4[v & 3] += p0 + p1;
        __hip_bfloat162 t2 = __float22bfloat162_rn(make_float2(p0, p1));
        pw[i][v] = *(unsigned*)&t2;
      }
  };

  auto pv_tile = [&](const unsigned short* Vc, unsigned (&pw)[2][8]) {
#pragma unroll
    for (int kk = 0; kk < 4; ++kk) {
      union { unsigned u[4]; short8 s8; } pb;
#pragma unroll
      for (int v = 0; v < 4; ++v) pb.u[v] = pw[kk >> 1][(kk & 1) * 4 + v];
#pragma unroll
      for (int d = 0; d < 2; ++d) {
        short8 vf = *(const short8*)&Vc[((kk * 2 + hh) * 64 + d * 32 + q31) * 8];
        o[d] = __builtin_amdgcn_mfma_f32_32x32x16_bf16(vf, pb.s8, o[d], 0, 0, 0);
      }
    }
  };

  const int st0 = half * 16, st1 = st0 + 16;
  stage(st0, 0);
  stage(st0 + 1, 1);
  for (int st = st0; st < st1; st += 2) {
    __syncthreads();  // drains vmcnt(0): bufs st&3,(st+1)&3 ready
    if (st + 2 < st1) { stage(st + 2, (st + 2) & 3); stage(st + 3, (st + 3) & 3); }
    f32x16 sfA[2], sfB[2];
    unsigned pwA[2][8], pwB[2][8];
    qk_tile(&Ks[(st & 3) * 4096], sfA);
    qk_tile(&Ks[((st + 1) & 3) * 4096], sfB);
    softmax_tile(sfA, st, pwA);
    pv_tile(&Vs[(st & 3) * 4096], pwA);
    softmax_tile(sfB, st + 1, pwB);
    pv_tile(&Vs[((st + 1) & 3) * 4096], pwB);
  }
  // epilogue: UNNORMALIZED bf16 O-partial + f32 l-partial
  float lrun = (rs4[0] + rs4[1]) + (rs4[2] + rs4[3]);
  lrun += __shfl_xor(lrun, 32);
  if (hh == 0) lpart[half * 65536 + bh * 2048 + q] = lrun;
  unsigned short* Op = half ? Op1 : Op0;
  unsigned short* orow = Op + ((size_t)b * 2048 + q) * 1024 + head * 64;
#pragma unroll
  for (int d = 0; d < 2; ++d)
#pragma unroll
    for (int g = 0; g < 4; ++g) {
      ushort4 pk4;
      pk4.x = f2bf(o[d][4 * g + 0]);
      pk4.y = f2bf(o[d][4 * g + 1]);
      pk4.z = f2bf(o[d][4 * g + 2]);
      pk4.w = f2bf(o[d][4 * g + 3]);
      *(ushort4*)&orow[32 * d + 8 * g + 4 * hh] = pk4;
    }
}

// ---------------- combine KV-split partials: O = (O0+O1)/(l0+l1) ------------
__global__ void combine_kernel(const unsigned short* __restrict__ p0,
                               const unsigned short* __restrict__ p1,
                               const float* __restrict__ lp,
                               unsigned short* __restrict__ Ob) {
  int idx = blockIdx.x * 256 + threadIdx.x;  // 524288 threads, 8 elems each
  int row = idx >> 7;                        // b*2048 + q
  int c8 = (idx & 127) << 3;                 // channel base (same head within 8)
  int head = c8 >> 6;
  int b = row >> 11, q = row & 2047;
  int bhq = (b * 16 + head) * 2048 + q;
  float inv = 1.f / (lp[bhq] + lp[65536 + bhq]);
  short8 a = *(const short8*)&p0[(size_t)row * 1024 + c8];
  short8 bb = *(const short8*)&p1[(size_t)row * 1024 + c8];
  short8 o8;
#pragma unroll
  for (int e = 0; e < 8; ++e)
    o8[e] = (short)f2bf((bf2f((unsigned short)a[e]) + bf2f((unsigned short)bb[e])) * inv);
  *(short8*)&Ob[(size_t)row * 1024 + c8] = o8;
}

extern "C" void kernel_launch(void* const* d_in, const int* in_sizes, int n_in,
                              void* d_out, int out_size, void* d_ws, size_t ws_size,
                              hipStream_t stream) {
  const float* qin  = (const float*)d_in[0];
  const float* kin  = (const float*)d_in[1];
  const float* vin  = (const float*)d_in[2];
  const float* mask = (const float*)d_in[3];
  const float* wq   = (const float*)d_in[4];
  const float* wk   = (const float*)d_in[5];
  const float* wv   = (const float*)d_in[6];
  const float* wo   = (const float*)d_in[7];

  float* out    = (float*)d_out;          // (B,L,1024)
  float* kcache = out + 4194304;          // (B,H,DK,S)
  float* vcache = kcache + 4194304;       // (B,H,S,DK)

  char* ws = (char*)d_ws;
  const size_t MB8 = 8388608ull;
  if (ws_size < 8 * MB8 + 4) return;
  unsigned short* xq  = (unsigned short*)(ws);
  unsigned short* xk  = (unsigned short*)(ws + MB8);
  unsigned short* xv  = (unsigned short*)(ws + 2 * MB8);
  unsigned short* wqb = (unsigned short*)(ws + 3 * MB8);
  unsigned short* wkb = (unsigned short*)(ws + 3 * MB8 + 2097152);
  unsigned short* wvb = (unsigned short*)(ws + 3 * MB8 + 2 * 2097152);
  unsigned short* wob = (unsigned short*)(ws + 3 * MB8 + 3 * 2097152);
  unsigned short* Qb  = (unsigned short*)(ws + 4 * MB8);
  unsigned short* Kb  = (unsigned short*)(ws + 5 * MB8);
  unsigned short* Vt  = (unsigned short*)(ws + 6 * MB8);
  unsigned short* Ob  = (unsigned short*)(ws + 7 * MB8);
  int* flag = (int*)(ws + 8 * MB8);
  // After gemm_qkv, xq/xk/xv are dead -> reuse for attention partials.
  unsigned short* Op0 = xq;                 // 8MB bf16 partial, KV half 0
  unsigned short* Op1 = xk;                 // 8MB bf16 partial, KV half 1
  float* lpart = (float*)(ws + 2 * MB8);    // 2 x 65536 f32 row sums (xv region)

  hipMemsetAsync(flag, 0, 4, stream);
  hipLaunchKernelGGL(cvt_kernel, dim3(20480), dim3(256), 0, stream,
                     qin, kin, vin, wq, wk, wv, wo, mask,
                     xq, xk, xv, wqb, wkb, wvb, wob, flag);
  hipLaunchKernelGGL(gemm_qkv_kernel, dim3(32, 8, 3), dim3(512), 0, stream,
                     xq, xk, xv, wqb, wkb, wvb, Qb, Kb, Vt, kcache, vcache);
  hipLaunchKernelGGL(attn_kernel, dim3(8, 32, 2), dim3(512), 0, stream,
                     Qb, Kb, Vt, mask, flag, Op0, Op1, lpart);
  hipLaunchKernelGGL(combine_kernel, dim3(2048), dim3(256), 0, stream,
                     Op0, Op1, lpart, Ob);
  hipLaunchKernelGGL(gemm_o_kernel, dim3(32, 8), dim3(512), 0, stream,
                     Ob, wob, out);
}

// Round 11
// 132.551 us; speedup vs baseline: 1.2364x; 1.2364x over previous
//
#include <hip/hip_runtime.h>
#include <hip/hip_bf16.h>

typedef __attribute__((ext_vector_type(4))) float f32x4;
typedef __attribute__((ext_vector_type(16))) float f32x16;
typedef __attribute__((ext_vector_type(8))) short short8;

#define LOG2E 1.4426950408889634f

__device__ __forceinline__ unsigned short f2bf(float f) {
  union { float f; unsigned u; } v; v.f = f;
  unsigned r = v.u + 0x7FFFu + ((v.u >> 16) & 1u);
  return (unsigned short)(r >> 16);
}

__device__ __forceinline__ void gload_lds16(const unsigned short* g, unsigned short* l) {
  __builtin_amdgcn_global_load_lds((const __attribute__((address_space(1))) void*)g,
                                   (__attribute__((address_space(3))) void*)l, 16, 0, 0);
}

// -------- weights f32 -> bf16 + mask nonzero flag (activations fused in GEMM) --------
__global__ void cvt_kernel(const float* __restrict__ wq, const float* __restrict__ wk,
                           const float* __restrict__ wv, const float* __restrict__ wo,
                           const float* __restrict__ mask,
                           unsigned short* __restrict__ wqb, unsigned short* __restrict__ wkb,
                           unsigned short* __restrict__ wvb, unsigned short* __restrict__ wob,
                           int* __restrict__ flag) {
  const size_t W1 = 262144;  // 1M f32 / 4 per unit
  size_t u = (size_t)blockIdx.x * 256 + threadIdx.x;
  const float* src; unsigned short* dst; size_t loc;
  if (u < W1)          { src = wq; dst = wqb; loc = u; }
  else if (u < 2 * W1) { src = wk; dst = wkb; loc = u - W1; }
  else if (u < 3 * W1) { src = wv; dst = wvb; loc = u - 2 * W1; }
  else if (u < 4 * W1) { src = wo; dst = wob; loc = u - 3 * W1; }
  else {
    loc = u - 4 * W1;  // mask: 4M f32 = 1M units
    float4 f = ((const float4*)mask)[loc];
    if (f.x != 0.f || f.y != 0.f || f.z != 0.f || f.w != 0.f) atomicOr(flag, 1);
    return;
  }
  float4 f = ((const float4*)src)[loc];
  ushort4 o;
  o.x = f2bf(f.x); o.y = f2bf(f.y); o.z = f2bf(f.z); o.w = f2bf(f.w);
  ((ushort4*)dst)[loc] = o;
}

// ---------------- QKV projections: C = A_f32 * B_bf16^T, fused conversion ----
// BM=BN=128, BK=32, 512 threads (8 waves, 4m x 2n). A staged via registers
// (f32 load -> f2bf -> ds_write_b128 at the pre-swizzled slot) with the T14
// issue-early/write-late split so HBM latency hides under the MFMA block.
// B staged via global_load_lds (bf16 weights). XOR-swizzled LDS, dbuf,
// 1 barrier per K-step. Buffer rotation: writeA targets the buffer freed by
// the last barrier (nobody reads it anymore).
__global__ __launch_bounds__(512)
void gemm_qkv_kernel(const float* __restrict__ qin, const float* __restrict__ kin,
                     const float* __restrict__ vin,
                     const unsigned short* __restrict__ wq, const unsigned short* __restrict__ wk,
                     const unsigned short* __restrict__ wv,
                     unsigned short* __restrict__ Qbf, unsigned short* __restrict__ Kbf,
                     unsigned short* __restrict__ Vt,
                     float* __restrict__ kcache, float* __restrict__ vcache) {
  __shared__ __align__(16) unsigned short As[2 * 4096];
  __shared__ __align__(16) unsigned short Bs[2 * 4096];
  const int z = blockIdx.z;
  const float* Af = (z == 0) ? qin : (z == 1) ? kin : vin;
  const unsigned short* B = (z == 0) ? wq : (z == 1) ? wk : wv;
  const int m0 = blockIdx.x * 128, n0 = blockIdx.y * 128;
  const int t = threadIdx.x, lane = t & 63, w = t >> 6;
  const int wr = (w >> 1) << 5, wc = (w & 1) << 6;
  const int lo = lane & 15, hi = lane >> 4;
  const int swz = (hi ^ ((lo >> 1) & 3)) * 8;

  f32x4 acc[2][4];
#pragma unroll
  for (int i = 0; i < 2; ++i)
#pragma unroll
    for (int j = 0; j < 4; ++j) acc[i][j] = f32x4{0.f, 0.f, 0.f, 0.f};

  const int c0 = t, row0 = c0 >> 2;
  const int gsw0 = ((c0 & 3) ^ ((row0 >> 1) & 3)) << 3;
  const float* Arow = Af + (size_t)(m0 + row0) * 1024 + gsw0;
  const unsigned short* Br0 = B + (size_t)(n0 + row0) * 1024 + gsw0;

  float4 a0, a1;
  auto loadA = [&](int kt) {
    a0 = *(const float4*)(Arow + kt);
    a1 = *(const float4*)(Arow + kt + 4);
  };
  auto writeA = [&](int buf) {
    short8 w8;
    w8[0] = (short)f2bf(a0.x); w8[1] = (short)f2bf(a0.y);
    w8[2] = (short)f2bf(a0.z); w8[3] = (short)f2bf(a0.w);
    w8[4] = (short)f2bf(a1.x); w8[5] = (short)f2bf(a1.y);
    w8[6] = (short)f2bf(a1.z); w8[7] = (short)f2bf(a1.w);
    *(short8*)&As[buf * 4096 + c0 * 8] = w8;
  };
  auto stageB = [&](int kt, int buf) { gload_lds16(Br0 + kt, &Bs[buf * 4096 + c0 * 8]); };

  loadA(0); stageB(0, 0); writeA(0);
  for (int it = 0; it < 32; ++it) {
    __syncthreads();  // buf it&1 ready (A ds_writes + B gload drained); (it+1)&1 free
    if (it + 1 < 32) { loadA((it + 1) * 32); stageB((it + 1) * 32, (it + 1) & 1); }
    const unsigned short* Ac = &As[(it & 1) * 4096];
    const unsigned short* Bc = &Bs[(it & 1) * 4096];
    short8 af[2], bfr[4];
#pragma unroll
    for (int i = 0; i < 2; ++i) af[i]  = *(const short8*)&Ac[(wr + i*16 + lo) * 32 + swz];
#pragma unroll
    for (int j = 0; j < 4; ++j) bfr[j] = *(const short8*)&Bc[(wc + j*16 + lo) * 32 + swz];
#pragma unroll
    for (int i = 0; i < 2; ++i)
#pragma unroll
      for (int j = 0; j < 4; ++j)
        acc[i][j] = __builtin_amdgcn_mfma_f32_16x16x32_bf16(af[i], bfr[j], acc[i][j], 0, 0, 0);
    if (it + 1 < 32) writeA((it + 1) & 1);  // late write: loads landed under the MFMAs
  }

#pragma unroll
  for (int i = 0; i < 2; ++i)
#pragma unroll
    for (int j = 0; j < 4; ++j) {
      int n = n0 + wc + j * 16 + lo;
      int head = n >> 6, dk = n & 63;
      int mbase = m0 + wr + i * 16 + hi * 4;
      int b = mbase >> 11, sbase = mbase & 2047;
      size_t bh = (size_t)b * 16 + head;
      if (z == 0) {
#pragma unroll
        for (int r = 0; r < 4; ++r)
          Qbf[(bh * 2048 + sbase + r) * 64 + dk] = f2bf(acc[i][j][r] * LOG2E);
      } else if (z == 1) {
#pragma unroll
        for (int r = 0; r < 4; ++r)
          Kbf[(bh * 2048 + sbase + r) * 64 + dk] = f2bf(acc[i][j][r]);
        float4 kv4;
        kv4.x = acc[i][j][0]; kv4.y = acc[i][j][1];
        kv4.z = acc[i][j][2]; kv4.w = acc[i][j][3];
        *(float4*)&kcache[(bh * 64 + dk) * 2048 + sbase] = kv4;
      } else {
#pragma unroll
        for (int r = 0; r < 4; ++r)
          vcache[(bh * 2048 + sbase + r) * 64 + dk] = acc[i][j][r];
        ushort4 vt4;
        vt4.x = f2bf(acc[i][j][0]); vt4.y = f2bf(acc[i][j][1]);
        vt4.z = f2bf(acc[i][j][2]); vt4.w = f2bf(acc[i][j][3]);
        *(ushort4*)&Vt[(bh * 64 + dk) * 2048 + sbase] = vt4;
      }
    }
}

// ---------------- output projection (bf16 x bf16 -> f32) ----------------
__global__ __launch_bounds__(512)
void gemm_o_kernel(const unsigned short* __restrict__ A, const unsigned short* __restrict__ B,
                   float* __restrict__ C) {
  __shared__ __align__(16) unsigned short As[2 * 4096];
  __shared__ __align__(16) unsigned short Bs[2 * 4096];
  const int m0 = blockIdx.x * 128, n0 = blockIdx.y * 128;
  const int t = threadIdx.x, lane = t & 63, w = t >> 6;
  const int wr = (w >> 1) << 5, wc = (w & 1) << 6;
  const int lo = lane & 15, hi = lane >> 4;
  const int swz = (hi ^ ((lo >> 1) & 3)) * 8;
  f32x4 acc[2][4];
#pragma unroll
  for (int i = 0; i < 2; ++i)
#pragma unroll
    for (int j = 0; j < 4; ++j) acc[i][j] = f32x4{0.f, 0.f, 0.f, 0.f};

  const int c0 = t, row0 = c0 >> 2;
  const int gsw0 = ((c0 & 3) ^ ((row0 >> 1) & 3)) << 3;
  const unsigned short* Ar0 = A + (size_t)(m0 + row0) * 1024 + gsw0;
  const unsigned short* Br0 = B + (size_t)(n0 + row0) * 1024 + gsw0;

  auto stage = [&](int kt, int buf) {
    gload_lds16(Ar0 + kt, &As[buf * 4096 + c0 * 8]);
    gload_lds16(Br0 + kt, &Bs[buf * 4096 + c0 * 8]);
  };

  stage(0, 0);
  for (int it = 0; it < 32; ++it) {
    __syncthreads();
    if (it + 1 < 32) stage((it + 1) * 32, (it + 1) & 1);
    const unsigned short* Ac = &As[(it & 1) * 4096];
    const unsigned short* Bc = &Bs[(it & 1) * 4096];
    short8 af[2], bfr[4];
#pragma unroll
    for (int i = 0; i < 2; ++i) af[i]  = *(const short8*)&Ac[(wr + i*16 + lo) * 32 + swz];
#pragma unroll
    for (int j = 0; j < 4; ++j) bfr[j] = *(const short8*)&Bc[(wc + j*16 + lo) * 32 + swz];
#pragma unroll
    for (int i = 0; i < 2; ++i)
#pragma unroll
      for (int j = 0; j < 4; ++j)
        acc[i][j] = __builtin_amdgcn_mfma_f32_16x16x32_bf16(af[i], bfr[j], acc[i][j], 0, 0, 0);
  }
#pragma unroll
  for (int i = 0; i < 2; ++i)
#pragma unroll
    for (int j = 0; j < 4; ++j)
#pragma unroll
      for (int r = 0; r < 4; ++r)
        C[(size_t)(m0 + wr + i * 16 + hi * 4 + r) * 1024 + n0 + wc + j * 16 + lo] = acc[i][j][r];
}

// ---------------- flash attention, swapped-operand 32x32 MFMA (round-8) -----
// Single-pass. 4 KV buffer pairs (64KB LDS), ONE barrier per TWO tiles;
// compute order QK(t) -> QK(t+1) -> exp(t) -> PV(t) -> exp(t+1) -> PV(t+1).
// Scale-invariant softmax in log2 domain (Q pre-scaled by log2e): P = exp2(s),
// no max subtraction. Row-sum l via ones-A MFMA.
__global__ __launch_bounds__(256, 2)
void attn_kernel(const unsigned short* __restrict__ Qbf,
                 const unsigned short* __restrict__ Kbf,
                 const unsigned short* __restrict__ Vtb,
                 const float* __restrict__ mask, const int* __restrict__ flag,
                 unsigned short* __restrict__ Obf) {
  __shared__ __align__(16) unsigned short Ks[4 * 4096];  // [buf][d8][slot64][8]
  __shared__ __align__(16) unsigned short Vs[4 * 4096];  // [buf][s8][dk64][8]
  const int t = threadIdx.x, lane = t & 63, w = t >> 6;
  const int q31 = lane & 31, hh = lane >> 5;

  int orig = blockIdx.x + 16 * blockIdx.y;
  int logical = (orig & 7) * 64 + (orig >> 3);
  const int bh = logical >> 4;
  const int b = bh >> 4, head = bh & 15;
  const int q = (logical & 15) * 128 + w * 32 + q31;
  const int mf = *flag;

  short8 qf[4];
  const unsigned short* Qrow = Qbf + ((size_t)bh * 2048 + q) * 64 + hh * 8;
#pragma unroll
  for (int kk = 0; kk < 4; ++kk) qf[kk] = *(const short8*)(Qrow + kk * 16);

  f32x16 o[2], osum, zero16;
#pragma unroll
  for (int d = 0; d < 2; ++d)
#pragma unroll
    for (int r = 0; r < 16; ++r) o[d][r] = 0.f;
#pragma unroll
  for (int r = 0; r < 16; ++r) { osum[r] = 0.f; zero16[r] = 0.f; }
  short8 ones8;
#pragma unroll
  for (int e = 0; e < 8; ++e) ones8[e] = (short)0x3F80;  // bf16 1.0

  const unsigned short* Kbase = Kbf + (size_t)bh * 2048 * 64;
  const unsigned short* Vbase = Vtb + (size_t)bh * 64 * 2048;

  auto stage = [&](int st, int buf) {
#pragma unroll
    for (int cc = 0; cc < 2; ++cc) {
      int c = t + cc * 256;
      int hi6 = c >> 6, lo6 = c & 63;
      int pr = (lo6 & ~12) | ((lo6 & 4) << 1) | ((lo6 >> 1) & 4);  // bit2<->bit3
      gload_lds16(Kbase + (size_t)(st * 64 + pr) * 64 + hi6 * 8, &Ks[buf * 4096 + c * 8]);
      gload_lds16(Vbase + (size_t)lo6 * 2048 + st * 64 + hi6 * 8, &Vs[buf * 4096 + c * 8]);
    }
  };

  auto qk_tile = [&](const unsigned short* Kc, f32x16 (&sf)[2]) {
#pragma unroll
    for (int kk = 0; kk < 4; ++kk)
#pragma unroll
      for (int i = 0; i < 2; ++i) {
        short8 kf = *(const short8*)&Kc[((kk * 2 + hh) * 64 + i * 32 + q31) * 8];
        sf[i] = __builtin_amdgcn_mfma_f32_32x32x16_bf16(kf, qf[kk],
                                                        kk == 0 ? zero16 : sf[i], 0, 0, 0);
      }
  };

  auto softmax_tile = [&](f32x16 (&sf)[2], int st, unsigned (&pw)[2][8]) {
    if (mf) {
      const float* mrow = mask + (size_t)q * 2048 + st * 64;
#pragma unroll
      for (int i = 0; i < 2; ++i)
#pragma unroll
        for (int r = 0; r < 16; ++r)
          sf[i][r] += mrow[32 * i + (r & 7) + 16 * ((r >> 3) & 1) + 8 * hh] * LOG2E;
    }
#pragma unroll
    for (int i = 0; i < 2; ++i)
#pragma unroll
      for (int v = 0; v < 8; ++v) {
        float p0 = __builtin_amdgcn_exp2f(sf[i][2 * v]);
        float p1 = __builtin_amdgcn_exp2f(sf[i][2 * v + 1]);
        __hip_bfloat162 t2 = __float22bfloat162_rn(make_float2(p0, p1));
        pw[i][v] = *(unsigned*)&t2;
      }
  };

  auto pv_tile = [&](const unsigned short* Vc, unsigned (&pw)[2][8]) {
#pragma unroll
    for (int kk = 0; kk < 4; ++kk) {
      union { unsigned u[4]; short8 s8; } pb;
#pragma unroll
      for (int v = 0; v < 4; ++v) pb.u[v] = pw[kk >> 1][(kk & 1) * 4 + v];
#pragma unroll
      for (int d = 0; d < 2; ++d) {
        short8 vf = *(const short8*)&Vc[((kk * 2 + hh) * 64 + d * 32 + q31) * 8];
        o[d] = __builtin_amdgcn_mfma_f32_32x32x16_bf16(vf, pb.s8, o[d], 0, 0, 0);
      }
      osum = __builtin_amdgcn_mfma_f32_32x32x16_bf16(ones8, pb.s8, osum, 0, 0, 0);
    }
  };

  stage(0, 0);
  stage(1, 1);
  for (int st = 0; st < 32; st += 2) {
    __syncthreads();
    if (st + 2 < 32) { stage(st + 2, (st + 2) & 3); stage(st + 3, (st + 3) & 3); }
    f32x16 sfA[2], sfB[2];
    unsigned pwA[2][8], pwB[2][8];
    qk_tile(&Ks[(st & 3) * 4096], sfA);
    qk_tile(&Ks[((st + 1) & 3) * 4096], sfB);
    softmax_tile(sfA, st, pwA);
    pv_tile(&Vs[(st & 3) * 4096], pwA);
    softmax_tile(sfB, st + 1, pwB);
    pv_tile(&Vs[((st + 1) & 3) * 4096], pwB);
  }
  float inv = 1.f / osum[0];
  unsigned short* orow = Obf + ((size_t)b * 2048 + q) * 1024 + head * 64;
#pragma unroll
  for (int d = 0; d < 2; ++d)
#pragma unroll
    for (int g = 0; g < 4; ++g) {
      ushort4 pk4;
      pk4.x = f2bf(o[d][4 * g + 0] * inv);
      pk4.y = f2bf(o[d][4 * g + 1] * inv);
      pk4.z = f2bf(o[d][4 * g + 2] * inv);
      pk4.w = f2bf(o[d][4 * g + 3] * inv);
      *(ushort4*)&orow[32 * d + 8 * g + 4 * hh] = pk4;
    }
}

extern "C" void kernel_launch(void* const* d_in, const int* in_sizes, int n_in,
                              void* d_out, int out_size, void* d_ws, size_t ws_size,
                              hipStream_t stream) {
  const float* qin  = (const float*)d_in[0];
  const float* kin  = (const float*)d_in[1];
  const float* vin  = (const float*)d_in[2];
  const float* mask = (const float*)d_in[3];
  const float* wq   = (const float*)d_in[4];
  const float* wk   = (const float*)d_in[5];
  const float* wv   = (const float*)d_in[6];
  const float* wo   = (const float*)d_in[7];

  float* out    = (float*)d_out;          // (B,L,1024)
  float* kcache = out + 4194304;          // (B,H,DK,S)
  float* vcache = kcache + 4194304;       // (B,H,S,DK)

  char* ws = (char*)d_ws;
  const size_t MB8 = 8388608ull;
  if (ws_size < 8 * MB8 + 4) return;
  unsigned short* wqb = (unsigned short*)(ws + 3 * MB8);
  unsigned short* wkb = (unsigned short*)(ws + 3 * MB8 + 2097152);
  unsigned short* wvb = (unsigned short*)(ws + 3 * MB8 + 2 * 2097152);
  unsigned short* wob = (unsigned short*)(ws + 3 * MB8 + 3 * 2097152);
  unsigned short* Qb  = (unsigned short*)(ws + 4 * MB8);
  unsigned short* Kb  = (unsigned short*)(ws + 5 * MB8);
  unsigned short* Vt  = (unsigned short*)(ws + 6 * MB8);
  unsigned short* Ob  = (unsigned short*)(ws + 7 * MB8);
  int* flag = (int*)(ws + 8 * MB8);

  hipMemsetAsync(flag, 0, 4, stream);
  hipLaunchKernelGGL(cvt_kernel, dim3(8192), dim3(256), 0, stream,
                     wq, wk, wv, wo, mask, wqb, wkb, wvb, wob, flag);
  hipLaunchKernelGGL(gemm_qkv_kernel, dim3(32, 8, 3), dim3(512), 0, stream,
                     qin, kin, vin, wqb, wkb, wvb, Qb, Kb, Vt, kcache, vcache);
  hipLaunchKernelGGL(attn_kernel, dim3(16, 32), dim3(256), 0, stream,
                     Qb, Kb, Vt, mask, flag, Ob);
  hipLaunchKernelGGL(gemm_o_kernel, dim3(32, 8), dim3(512), 0, stream,
                     Ob, wob, out);
}